// Round 20
// baseline (466.432 us; speedup 1.0000x reference)
//
#include <hip/hip_runtime.h>
#include <math.h>

#define BN_RS 0.9995003746877732f

typedef unsigned short u16;
typedef _Float16 f16;
typedef __attribute__((ext_vector_type(8))) _Float16 h8v;     // 8 f16 (A/B frag)
typedef __attribute__((ext_vector_type(4))) _Float16 h4v;     // packed 4 f16 (8B)
typedef __attribute__((ext_vector_type(2))) __fp16 fp16x2;    // cvt_pkrtz native type
typedef __attribute__((ext_vector_type(4))) float f32x4;      // 16x16 C/D frag
typedef __attribute__((ext_vector_type(16))) float f32x16;    // 32x32 C/D frag

// ---------------- helpers ----------------
__device__ __forceinline__ unsigned f2mono(float f){
  unsigned u = __float_as_uint(f);
  return (u & 0x80000000u) ? ~u : (u | 0x80000000u);
}
__device__ __forceinline__ float mono2f(unsigned m){
  unsigned u = (m & 0x80000000u) ? (m & 0x7FFFFFFFu) : ~m;
  return __uint_as_float(u);
}
__device__ __forceinline__ float silu_fast(float x){
  float e = __expf(-x);
  return x * __builtin_amdgcn_rcpf(1.f + e);      // v_rcp_f32: 1-ulp
}
__device__ __forceinline__ float silu_f64(float x){
  double e = exp(-(double)x);
  return (float)((double)x / (1.0 + e));
}
// pack 4 f32 -> 4 f16 with 2 v_cvt_pkrtz_f16_f32 instructions
__device__ __forceinline__ h4v pkrtz4(float a, float b, float c, float d){
  fp16x2 lo = __builtin_amdgcn_cvt_pkrtz(a, b);
  fp16x2 hi = __builtin_amdgcn_cvt_pkrtz(c, d);
  unsigned lu = __builtin_bit_cast(unsigned, lo);
  unsigned hu = __builtin_bit_cast(unsigned, hi);
  unsigned long long packed = ((unsigned long long)hu << 32) | lu;
  return __builtin_bit_cast(h4v, packed);
}

// ---------------- ws layout (bytes) ----------------
constexpr size_t OFF_T9   = 0;         //  4*9*4
constexpr size_t OFF_XM   = 1024;      //  4*128*4 (mono uints)
constexpr size_t OFF_PC4  = 4096;      //  8192*16
constexpr size_t OFF_OUT  = 139264;    //  21760*4
constexpr size_t OFF_C1T  = 227328;    //  512*32*2   (frag32-packed, BN-folded)
constexpr size_t OFF_B0C  = 262144;    //  512*512*2  (frag32-packed, composed (I+R)@W0)
constexpr size_t OFF_B1T  = 1310720;   //  256*512*2  (frag32-packed, BN-folded)
constexpr size_t OFF_B2T  = 1572864;   //  176*256*2  (frag16-packed, BN-folded)
constexpr size_t OFF_BS1  = 1662976;   //  512*4 bias (BN-folded)
constexpr size_t OFF_BS0  = 1667072;   //  512*4 (composed)
constexpr size_t OFF_BSB1 = 1669120;   //  256*4
constexpr size_t OFF_BSB2 = 1670144;   //  176*4  (ends 1670848 < OFF_F9)
constexpr size_t OFF_F9   = 1703936;   //  8192*32*16*2

// ---------------- T-Net stage 1 ----------------
__global__ void tnet1_kernel(const float* __restrict__ pts, const float* __restrict__ t_cw,
                             const float* __restrict__ t_cb, const float* __restrict__ t_g1,
                             const float* __restrict__ t_b1, unsigned* __restrict__ xm_mono){
  int u = threadIdx.x;                 // 0..127
  int b = blockIdx.x;                  // 0..3
  int slice = blockIdx.y * blockDim.y + threadIdx.y;   // 0..15
  float w0 = t_cw[u], w1 = t_cw[128+u], w2 = t_cw[256+u];
  float cb = t_cb[u];
  float sc = __fmul_rn(BN_RS, t_g1[u]);
  float b1 = t_b1[u];
  float mx = -INFINITY;
  const float* P = pts + ((size_t)b*2048 + (size_t)slice*128)*3;
  for (int n = 0; n < 128; ++n){
    float y = __fadd_rn(__fadd_rn(__fmul_rn(P[n*3+0], w0), __fmul_rn(P[n*3+1], w1)),
                        __fmul_rn(P[n*3+2], w2));
    y = __fadd_rn(y, cb);
    y = __fadd_rn(__fmul_rn(y, sc), b1);
    mx = fmaxf(mx, silu_f64(y));
  }
  atomicMax(&xm_mono[b*128+u], f2mono(mx));
}

// ---------------- T-Net stage 2 (f64 accum) ----------------
__global__ void tnet2_kernel(const unsigned* __restrict__ xm_mono,
                             const float* __restrict__ d1w, const float* __restrict__ d1b,
                             const float* __restrict__ g2, const float* __restrict__ b2,
                             const float* __restrict__ d2w, const float* __restrict__ d2b,
                             float* __restrict__ T9){
  __shared__ float xs[128], x2s[128];
  int u = threadIdx.x, b = blockIdx.x;
  xs[u] = mono2f(xm_mono[b*128+u]);
  __syncthreads();
  double acc = (double)d1b[u];
  for (int v = 0; v < 128; ++v) acc += (double)xs[v] * (double)d1w[v*128+u];
  double sc = (double)__fmul_rn(BN_RS, g2[u]);
  acc = acc*sc + (double)b2[u];
  double e = exp(-acc);
  x2s[u] = (float)(acc / (1.0 + e));
  __syncthreads();
  if (u < 9){
    double t = (double)d2b[u];
    for (int v = 0; v < 128; ++v) t += (double)x2s[v] * (double)d2w[v*9+u];
    T9[b*9+u] = (float)t;
  }
}

// ---------------- pc = pts @ T (np order, no fma) + sq ----------------
__global__ void pc_kernel(const float* __restrict__ pts, const float* __restrict__ T9,
                          float4* __restrict__ pc4){
  int i = blockIdx.x*blockDim.x + threadIdx.x;   // 0..8191
  int b = i >> 11;
  const float* p = pts + (size_t)i*3;
  float x = p[0], y = p[1], z = p[2];
  const float* T = T9 + b*9;
  float px = __fadd_rn(__fadd_rn(__fmul_rn(x, T[0]), __fmul_rn(y, T[3])), __fmul_rn(z, T[6]));
  float py = __fadd_rn(__fadd_rn(__fmul_rn(x, T[1]), __fmul_rn(y, T[4])), __fmul_rn(z, T[7]));
  float pz = __fadd_rn(__fadd_rn(__fmul_rn(x, T[2]), __fmul_rn(y, T[5])), __fmul_rn(z, T[8]));
  float sq = __fadd_rn(__fadd_rn(__fmul_rn(px, px), __fmul_rn(py, py)), __fmul_rn(pz, pz));
  pc4[i] = make_float4(px, py, pz, sq);
}

// ---------------- grouping: no LDS staging (pc4 is L1/L2-resident) ----------------
__global__ __launch_bounds__(256) void group_kernel(const float4* __restrict__ pc4,
                                                    f16* __restrict__ f9){
  __shared__ int ones[4][3][32];
  __shared__ int zer [4][3][32];
  const float RAD[3] = {0.1f, 0.3f, 0.5f};
  int tid = threadIdx.x, wave = tid >> 6, lane = tid & 63;
  int bid = blockIdx.x;
  int b = bid >> 9, n0 = (bid & 511) * 4;
  const float4* src = pc4 + (size_t)b*2048;

  int n = n0 + wave;
  float4 pi = src[n];
  float xi = pi.x, yi = pi.y, zi = pi.z, sqi = pi.w;
  int c1[3] = {0,0,0}, c0[3] = {0,0,0};
  unsigned long long lt = (1ULL << lane) - 1ULL;

  for (int ch = 0; ch < 32; ++ch){
    int j = ch*64 + lane;
    float4 pj = src[j];
    float dot = __fadd_rn(__fadd_rn(__fmul_rn(xi, pj.x), __fmul_rn(yi, pj.y)),
                          __fmul_rn(zi, pj.z));
    float d2 = __fsub_rn(__fadd_rn(sqi, pj.w), __fmul_rn(2.f, dot));
    float dist = sqrtf(fmaxf(d2, 0.f));
    #pragma unroll
    for (int ri = 0; ri < 3; ++ri){
      bool in = (dist <= RAD[ri]);
      unsigned long long m = __ballot(in);
      int pc_lt = (int)__popcll(m & lt);
      if (c1[ri] < 32){
        int pos = c1[ri] + pc_lt;
        if (in && pos < 32) ones[wave][ri][pos] = j;
      }
      if (c0[ri] < 32){
        int pos = c0[ri] + (int)(lane - pc_lt);
        if (!in && pos < 32) zer[wave][ri][pos] = j;
      }
      int t1 = (int)__popcll(m);
      c1[ri] += t1;
      c0[ri] += 64 - t1;
    }
    if (c1[0] >= 32 && c1[1] >= 32 && c1[2] >= 32 &&
        c0[0] >= 32 && c0[1] >= 32 && c0[2] >= 32) break;
  }

  if (lane < 32){
    h8v va, vb;
    #pragma unroll
    for (int t = 0; t < 8; ++t){ va[t] = (f16)0.f; vb[t] = (f16)0.f; }
    #pragma unroll
    for (int ri = 0; ri < 3; ++ri){
      int cc = c1[ri] < 32 ? c1[ri] : 32;
      int sel = (lane < cc) ? ones[wave][ri][lane] : zer[wave][ri][lane - cc];
      float4 p = src[sel];
      if (ri == 0){ va[0]=(f16)p.x; va[1]=(f16)p.y; va[2]=(f16)p.z; }
      if (ri == 1){ va[3]=(f16)p.x; va[4]=(f16)p.y; va[5]=(f16)p.z; }
      if (ri == 2){ va[6]=(f16)p.x; va[7]=(f16)p.y; vb[0]=(f16)p.z; }
    }
    f16* dst = f9 + (((size_t)(b*2048 + n) * 32 + lane) << 4);
    *(h8v*)dst = va;
    *(h8v*)(dst + 8) = vb;
  }
}

// ---------------- weight prep ----------------
// 32x32 fragment pack: dst[((sct*NT16 + t)*64 + lane)*8 + j] = W[ci][co]*g
// co = sct*32 + (lane&31), ci = t*16 + ((lane>>5)<<3) + j
__device__ __forceinline__ void pack_frag32(const float* __restrict__ src, f16* __restrict__ dst,
                                            int CO, int CI, int COr, int CIr,
                                            const float* __restrict__ g,
                                            int i0, int stride){
  int NT16 = CI >> 4;
  int total = (CO >> 5) * NT16 * 512;
  for (int x = i0; x < total; x += stride){
    int j = x & 7, lane = (x >> 3) & 63;
    int t = (x >> 9) % NT16, sct = x / (NT16 << 9);
    int co = sct*32 + (lane & 31);
    int ci = t*16 + ((lane >> 5) << 3) + j;
    float v = 0.f;
    if (co < COr && ci < CIr){
      v = src[ci*COr + co];
      if (g) v *= BN_RS * g[co];
    }
    dst[x] = (f16)v;
  }
}
// 16x16 fragment pack (blk2 only)
__device__ __forceinline__ void pack_frag16(const float* __restrict__ src, f16* __restrict__ dst,
                                            int CO, int CI, int COr, int CIr,
                                            const float* __restrict__ g,
                                            int i0, int stride){
  int NT = CI >> 5;
  int total = (CO >> 4) * NT * 512;
  for (int x = i0; x < total; x += stride){
    int j = x & 7, lane = (x >> 3) & 63;
    int t = (x >> 9) % NT, sct = x / (NT << 9);
    int co = sct*16 + (lane & 15);
    int ci = t*32 + (lane >> 4)*8 + j;
    float v = 0.f;
    if (co < COr && ci < CIr){
      v = src[ci*COr + co];
      if (g) v *= BN_RS * g[co];
    }
    dst[x] = (f16)v;
  }
}

__global__ void prep_kernel(const float* __restrict__ c1w,
                            const float* __restrict__ b0w, const float* __restrict__ b1w,
                            const float* __restrict__ b2w,
                            const float* __restrict__ c1_b, const float* __restrict__ c1_g, const float* __restrict__ c1_be,
                            const float* __restrict__ res_b,
                            const float* __restrict__ b0_b, const float* __restrict__ b0_g, const float* __restrict__ b0_be,
                            const float* __restrict__ b1_b, const float* __restrict__ b1_g, const float* __restrict__ b1_be,
                            const float* __restrict__ b2_b, const float* __restrict__ b2_g, const float* __restrict__ b2_be,
                            f16* __restrict__ c1F, f16* __restrict__ b1F, f16* __restrict__ b2F,
                            float* __restrict__ bs1, float* __restrict__ bs0,
                            float* __restrict__ bsb1, float* __restrict__ bsb2){
  int i0 = blockIdx.x*blockDim.x + threadIdx.x;
  int stride = gridDim.x*blockDim.x;
  pack_frag32(c1w,  c1F,  512,  32, 512,   9, c1_g, i0, stride);
  pack_frag32(b1w,  b1F,  256, 512, 256, 512, b1_g, i0, stride);
  pack_frag16(b2w,  b2F,  176, 256, 170, 256, b2_g, i0, stride);
  for (int x = i0; x < 512; x += stride){
    bs1[x] = c1_b[x]*(BN_RS*c1_g[x]) + c1_be[x];
    float s = b0_b[x];
    for (int m = 0; m < 512; ++m) s = fmaf(res_b[m], b0w[m*512 + x], s);
    bs0[x] = s*(BN_RS*b0_g[x]) + b0_be[x];
  }
  for (int x = i0; x < 256; x += stride) bsb1[x] = b1_b[x]*(BN_RS*b1_g[x]) + b1_be[x];
  for (int x = i0; x < 176; x += stride)
    bsb2[x] = (x < 170) ? b2_b[x]*(BN_RS*b2_g[x]) + b2_be[x] : 0.f;
}

// ---------------- tiled compose (I+R)@W0, BN-fold, frag32-packed f16 out ----------------
__global__ __launch_bounds__(256) void composeb0_kernel(const float* __restrict__ resw,
                                                        const float* __restrict__ b0w,
                                                        const float* __restrict__ b0_g,
                                                        f16* __restrict__ b0C){
  __shared__ float Rt[64][129];
  __shared__ float Wt[128][17];
  const int tid = threadIdx.x;
  const int co0 = (blockIdx.x & 31) * 16;
  const int ci0 = (blockIdx.x >> 5) * 64;
  const int r  = tid >> 2;
  const int cq = tid & 3;
  float acc[4] = {0.f, 0.f, 0.f, 0.f};

  for (int mc = 0; mc < 512; mc += 128){
    {
      int row = tid >> 2, mb = (tid & 3) * 32;
      const float* src = resw + (size_t)(ci0 + row)*512 + mc + mb;
      #pragma unroll
      for (int i = 0; i < 8; ++i){
        float4 v = *(const float4*)(src + i*4);
        Rt[row][mb + i*4 + 0] = v.x; Rt[row][mb + i*4 + 1] = v.y;
        Rt[row][mb + i*4 + 2] = v.z; Rt[row][mb + i*4 + 3] = v.w;
      }
    }
    {
      int m = tid >> 1, c8 = (tid & 1) * 8;
      const float* src = b0w + (size_t)(mc + m)*512 + co0 + c8;
      float4 v0 = *(const float4*)(src);
      float4 v1 = *(const float4*)(src + 4);
      Wt[m][c8+0] = v0.x; Wt[m][c8+1] = v0.y; Wt[m][c8+2] = v0.z; Wt[m][c8+3] = v0.w;
      Wt[m][c8+4] = v1.x; Wt[m][c8+5] = v1.y; Wt[m][c8+6] = v1.z; Wt[m][c8+7] = v1.w;
    }
    __syncthreads();
    #pragma unroll 8
    for (int m = 0; m < 128; ++m){
      float rv = Rt[r][m];
      #pragma unroll
      for (int i = 0; i < 4; ++i)
        acc[i] = fmaf(rv, Wt[m][cq*4 + i], acc[i]);
    }
    __syncthreads();
  }
  int ci = ci0 + r;
  #pragma unroll
  for (int i = 0; i < 4; ++i){
    int co = co0 + cq*4 + i;
    float s = acc[i] + b0w[(size_t)ci*512 + co];   // e_ci term of (I+R)
    s *= BN_RS * b0_g[co];
    // frag32 scatter (NT16 = 32): sct=co>>5, t=ci>>4, lane=(co&31)|(((ci>>3)&1)<<5), j=ci&7
    int sct = co >> 5, t = ci >> 4;
    int lane = (co & 31) | (((ci >> 3) & 1) << 5);
    int j = ci & 7;
    b0C[((size_t)(sct*32 + t)*64 + lane)*8 + j] = (f16)s;
  }
}

// ---------------- MLP (32-row tiles, 32x32 MFMA, 4 waves/SIMD) ----------------
// act tile: 32 rows x 512 f16, stride 1024 B, XOR-swizzled by ((row&7)<<4)
__device__ __forceinline__ int swzb(int row, int c){
  return (row*1024 + c*2) ^ ((row & 7) << 4);
}

// 32x32 register-streamed layer: act B-operand lane: row=lane&31, ci-half=lane>>5.
template<int NT16, int NCT>
__device__ __forceinline__ void mm32(const char* actc, const f16* __restrict__ WF,
                                     int sct0, int lane, f32x16 (&acc)[NCT]){
  const int ln = lane & 31, hi = lane >> 5;
  const int xr = (ln & 7) << 4;
  #pragma unroll
  for (int t = 0; t < NT16; ++t){
    int koff = (t*32 + (hi << 4)) ^ xr;
    h8v a = *(const h8v*)(actc + ln*1024 + koff);
    #pragma unroll
    for (int ct = 0; ct < NCT; ++ct){
      h8v w = *(const h8v*)&WF[((size_t)((sct0 + ct)*NT16 + t)*64 + lane)*8];
      acc[ct] = __builtin_amdgcn_mfma_f32_32x32x16_f16(w, a, acc[ct], 0, 0, 0);
    }
  }
}

// 32x32 silu epilogue: reg r: ch_local = (r&3)+8*(r>>2)+4*hi, row = ln.
template<int NCT>
__device__ __forceinline__ void epi32(char* outc, int co0, const float* __restrict__ bias,
                                      int lane, f32x16 (&acc)[NCT]){
  const int ln = lane & 31, hi = lane >> 5;
  #pragma unroll
  for (int ct = 0; ct < NCT; ++ct){
    #pragma unroll
    for (int q = 0; q < 4; ++q){
      int ch = co0 + ct*32 + q*8 + hi*4;
      float4 b4 = *(const float4*)(bias + ch);
      *(h4v*)(outc + swzb(ln, ch)) = pkrtz4(
          silu_fast(acc[ct][q*4+0] + b4.x),
          silu_fast(acc[ct][q*4+1] + b4.y),
          silu_fast(acc[ct][q*4+2] + b4.z),
          silu_fast(acc[ct][q*4+3] + b4.w));
    }
  }
}

__global__ __launch_bounds__(512, 4) void mlp_kernel(
    const f16* __restrict__ f9,
    const f16* __restrict__ c1F, const f16* __restrict__ b0C,
    const f16* __restrict__ b1F, const f16* __restrict__ b2F,
    const float* __restrict__ bs1, const float* __restrict__ bs0,
    const float* __restrict__ bsb1, const float* __restrict__ bsb2,
    unsigned* __restrict__ outmax){
  __shared__ __align__(16) f16 bufA[32*512];      // ping-pong act buffers (32 KiB each)
  __shared__ __align__(16) f16 bufB[32*512];
  char* A = (char*)bufA;
  char* B = (char*)bufB;
  const int tid  = threadIdx.x;
  const int wave = tid >> 6, lane = tid & 63;
  const int ln = lane & 31, hi = lane >> 5;
  const int lrow = lane & 15, lkg = lane >> 4;    // 16x16 path (blk2)
  const int bid = blockIdx.x;
  const int b = bid >> 11, k = (bid >> 6) & 31, n0 = (bid & 63) << 5;

  // stage f9 rows [32][32] into bufA front region (cols 16..31 zero)
  if (tid < 128){
    int row = tid >> 2, part = tid & 3;
    h8v v;
    if (part < 2){
      const f16* src = f9 + (((size_t)(b*2048 + n0 + row) * 32 + k) << 4) + part*8;
      v = *(const h8v*)src;
    } else {
      #pragma unroll
      for (int t = 0; t < 8; ++t) v[t] = (f16)0.f;
    }
    *(h8v*)&bufA[row*32 + part*8] = v;
  }
  __syncthreads();

  const f32x16 zf16 = {0.f,0.f,0.f,0.f,0.f,0.f,0.f,0.f,0.f,0.f,0.f,0.f,0.f,0.f,0.f,0.f};
  f32x16 acc[2];

  // ---- layer 1: Ci=32 (padded 9), Co=512, A(front [32][32]) -> B ----
  acc[0] = zf16; acc[1] = zf16;
  #pragma unroll
  for (int t = 0; t < 2; ++t){
    h8v a = *(const h8v*)(A + ln*64 + t*32 + hi*16);   // front region, no swizzle
    #pragma unroll
    for (int ct = 0; ct < 2; ++ct){
      h8v w = *(const h8v*)&c1F[((size_t)((wave*2 + ct)*2 + t)*64 + lane)*8];
      acc[ct] = __builtin_amdgcn_mfma_f32_32x32x16_f16(w, a, acc[ct], 0, 0, 0);
    }
  }
  epi32<2>(B, wave*64, bs1, lane, acc);
  __syncthreads();

  // ---- blk0': composed (I+R)@W0, 512 -> 512, B -> A ----
  acc[0] = zf16; acc[1] = zf16;
  mm32<32, 2>(B, b0C, wave*2, lane, acc);
  epi32<2>(A, wave*64, bs0, lane, acc);
  __syncthreads();

  // ---- blk1: 512 -> 256, A -> B (cols 0..255) ----
  f32x16 acc1[1];
  acc1[0] = zf16;
  mm32<32, 1>(A, b1F, wave, lane, acc1);
  epi32<1>(B, wave*32, bsb1, lane, acc1);
  __syncthreads();

  // ---- blk2: 256 -> 170 (pad 176), 16x16 path, B as A-operand, + row-max + atomic ----
  const f32x4 zf = {0.f, 0.f, 0.f, 0.f};
  f32x4 acc3[2][2];
  #pragma unroll
  for (int mt = 0; mt < 2; ++mt){ acc3[mt][0] = zf; acc3[mt][1] = zf; }
  {
    const int xr = (lrow & 7) << 4;
    const bool has2 = wave < 3;                    // wave+8 < 11
    #pragma unroll
    for (int t = 0; t < 8; ++t){
      h8v a[2];
      int koff = ((t*4 + lkg) << 4) ^ xr;
      #pragma unroll
      for (int mt = 0; mt < 2; ++mt)
        a[mt] = *(const h8v*)(B + (mt*16 + lrow)*1024 + koff);
      {
        h8v w = *(const h8v*)&b2F[((size_t)(wave*8 + t)*64 + lane)*8];
        #pragma unroll
        for (int mt = 0; mt < 2; ++mt)
          acc3[mt][0] = __builtin_amdgcn_mfma_f32_16x16x32_f16(a[mt], w, acc3[mt][0], 0, 0, 0);
      }
      if (has2){
        h8v w = *(const h8v*)&b2F[((size_t)((wave + 8)*8 + t)*64 + lane)*8];
        #pragma unroll
        for (int mt = 0; mt < 2; ++mt)
          acc3[mt][1] = __builtin_amdgcn_mfma_f32_16x16x32_f16(a[mt], w, acc3[mt][1], 0, 0, 0);
      }
    }
    #pragma unroll
    for (int t = 0; t < 2; ++t){
      if (t == 1 && !has2) break;
      int c = ((t == 0) ? wave : wave + 8)*16 + lrow;
      if (c < 170){
        float bb = bsb2[c];
        float mx = -INFINITY;
        #pragma unroll
        for (int mt = 0; mt < 2; ++mt)
          #pragma unroll
          for (int rg = 0; rg < 4; ++rg)
            mx = fmaxf(mx, silu_fast(acc3[mt][t][rg] + bb));
        mx = fmaxf(mx, __shfl_xor(mx, 16));
        mx = fmaxf(mx, __shfl_xor(mx, 32));
        if (lkg == 0)
          atomicMax(&outmax[b*5440 + k*170 + c], f2mono(mx));
      }
    }
  }
}

__global__ void finalize_kernel(const unsigned* __restrict__ m, float* __restrict__ out, int n){
  int i = blockIdx.x*blockDim.x + threadIdx.x;
  if (i < n) out[i] = mono2f(m[i]);
}

// ---------------- launch ----------------
extern "C" void kernel_launch(void* const* d_in, const int* in_sizes, int n_in,
                              void* d_out, int out_size, void* d_ws, size_t ws_size,
                              hipStream_t stream){
  const float* pts    = (const float*)d_in[0];
  const float* t_cw   = (const float*)d_in[1];
  const float* t_cb   = (const float*)d_in[2];
  const float* t_g1   = (const float*)d_in[3];
  const float* t_b1   = (const float*)d_in[4];
  const float* t_d1w  = (const float*)d_in[5];
  const float* t_d1b  = (const float*)d_in[6];
  const float* t_g2   = (const float*)d_in[7];
  const float* t_b2   = (const float*)d_in[8];
  const float* t_d2w  = (const float*)d_in[9];
  const float* t_d2b  = (const float*)d_in[10];
  const float* c1_w   = (const float*)d_in[11];
  const float* c1_b   = (const float*)d_in[12];
  const float* c1_g   = (const float*)d_in[13];
  const float* c1_be  = (const float*)d_in[14];
  const float* res_w  = (const float*)d_in[15];
  const float* res_b  = (const float*)d_in[16];
  const float* b0_w   = (const float*)d_in[17];
  const float* b0_b   = (const float*)d_in[18];
  const float* b0_g   = (const float*)d_in[19];
  const float* b0_be  = (const float*)d_in[20];
  const float* b1_w   = (const float*)d_in[21];
  const float* b1_b   = (const float*)d_in[22];
  const float* b1_g   = (const float*)d_in[23];
  const float* b1_be  = (const float*)d_in[24];
  const float* b2_w   = (const float*)d_in[25];
  const float* b2_b   = (const float*)d_in[26];
  const float* b2_g   = (const float*)d_in[27];
  const float* b2_be  = (const float*)d_in[28];

  char* ws = (char*)d_ws;
  float*    T9   = (float*)(ws + OFF_T9);
  unsigned* XM   = (unsigned*)(ws + OFF_XM);
  float4*   PC4  = (float4*)(ws + OFF_PC4);
  unsigned* OUTM = (unsigned*)(ws + OFF_OUT);
  f16* C1F  = (f16*)(ws + OFF_C1T);
  f16* B0C  = (f16*)(ws + OFF_B0C);
  f16* B1F  = (f16*)(ws + OFF_B1T);
  f16* B2F  = (f16*)(ws + OFF_B2T);
  float* BS1  = (float*)(ws + OFF_BS1);
  float* BS0  = (float*)(ws + OFF_BS0);
  float* BSB1 = (float*)(ws + OFF_BSB1);
  float* BSB2 = (float*)(ws + OFF_BSB2);
  f16* F9   = (f16*)(ws + OFF_F9);

  hipMemsetAsync(ws + OFF_XM, 0, 4*128*4, stream);
  hipMemsetAsync(ws + OFF_OUT, 0, 21760*4, stream);

  prep_kernel<<<512, 256, 0, stream>>>(c1_w, b0_w, b1_w, b2_w,
                                       c1_b, c1_g, c1_be, res_b,
                                       b0_b, b0_g, b0_be,
                                       b1_b, b1_g, b1_be,
                                       b2_b, b2_g, b2_be,
                                       C1F, B1F, B2F,
                                       BS1, BS0, BSB1, BSB2);
  composeb0_kernel<<<256, 256, 0, stream>>>(res_w, b0_w, b0_g, B0C);
  tnet1_kernel<<<dim3(4,4), dim3(128,4), 0, stream>>>(pts, t_cw, t_cb, t_g1, t_b1, XM);
  tnet2_kernel<<<4, 128, 0, stream>>>(XM, t_d1w, t_d1b, t_g2, t_b2, t_d2w, t_d2b, T9);
  pc_kernel<<<32, 256, 0, stream>>>(pts, T9, PC4);
  group_kernel<<<2048, 256, 0, stream>>>(PC4, F9);
  mlp_kernel<<<8192, 512, 0, stream>>>(F9, C1F, B0C, B1F, B2F,
                                       BS1, BS0, BSB1, BSB2, OUTM);
  finalize_kernel<<<(out_size + 255)/256, 256, 0, stream>>>(OUTM, (float*)d_out, out_size);
}

// Round 21
// 454.132 us; speedup vs baseline: 1.0271x; 1.0271x over previous
//
#include <hip/hip_runtime.h>
#include <math.h>

#define BN_RS 0.9995003746877732f

typedef unsigned short u16;
typedef _Float16 f16;
typedef __attribute__((ext_vector_type(8))) _Float16 h8v;     // 8 f16 (A/B frag)
typedef __attribute__((ext_vector_type(4))) _Float16 h4v;     // packed 4 f16 (8B)
typedef __attribute__((ext_vector_type(2))) __fp16 fp16x2;    // cvt_pkrtz native type
typedef __attribute__((ext_vector_type(4))) float f32x4;      // 16x16 C/D frag
typedef __attribute__((ext_vector_type(16))) float f32x16;    // 32x32 C/D frag

// ---------------- helpers ----------------
__device__ __forceinline__ unsigned f2mono(float f){
  unsigned u = __float_as_uint(f);
  return (u & 0x80000000u) ? ~u : (u | 0x80000000u);
}
__device__ __forceinline__ float mono2f(unsigned m){
  unsigned u = (m & 0x80000000u) ? (m & 0x7FFFFFFFu) : ~m;
  return __uint_as_float(u);
}
__device__ __forceinline__ float silu_fast(float x){
  float e = __expf(-x);
  return x * __builtin_amdgcn_rcpf(1.f + e);      // v_rcp_f32: 1-ulp
}
__device__ __forceinline__ float silu_f64(float x){
  double e = exp(-(double)x);
  return (float)((double)x / (1.0 + e));
}
// pack 4 f32 -> 4 f16 with 2 v_cvt_pkrtz_f16_f32 instructions
__device__ __forceinline__ h4v pkrtz4(float a, float b, float c, float d){
  fp16x2 lo = __builtin_amdgcn_cvt_pkrtz(a, b);
  fp16x2 hi = __builtin_amdgcn_cvt_pkrtz(c, d);
  unsigned lu = __builtin_bit_cast(unsigned, lo);
  unsigned hu = __builtin_bit_cast(unsigned, hi);
  unsigned long long packed = ((unsigned long long)hu << 32) | lu;
  return __builtin_bit_cast(h4v, packed);
}

// ---------------- ws layout (bytes) ----------------
constexpr size_t OFF_T9   = 0;         //  4*9*4
constexpr size_t OFF_XM   = 1024;      //  4*128*4 (mono uints)
constexpr size_t OFF_PC4  = 4096;      //  8192*16
constexpr size_t OFF_OUT  = 139264;    //  21760*4
constexpr size_t OFF_C1T  = 227328;    //  512*32*2   (frag32-packed, BN-folded)
constexpr size_t OFF_B0C  = 262144;    //  512*512*2  (frag32-packed, composed (I+R)@W0)
constexpr size_t OFF_B1T  = 1310720;   //  256*512*2  (frag32-packed, BN-folded)
constexpr size_t OFF_B2T  = 1572864;   //  176*256*2  (frag16-packed, BN-folded)
constexpr size_t OFF_BS1  = 1662976;   //  512*4 bias (BN-folded)
constexpr size_t OFF_BS0  = 1667072;   //  512*4 (composed)
constexpr size_t OFF_BSB1 = 1669120;   //  256*4
constexpr size_t OFF_BSB2 = 1670144;   //  176*4  (ends 1670848 < OFF_F9)
constexpr size_t OFF_F9   = 1703936;   //  8192*32*16*2

// ---------------- T-Net stage 1 ----------------
__global__ void tnet1_kernel(const float* __restrict__ pts, const float* __restrict__ t_cw,
                             const float* __restrict__ t_cb, const float* __restrict__ t_g1,
                             const float* __restrict__ t_b1, unsigned* __restrict__ xm_mono){
  int u = threadIdx.x;                 // 0..127
  int b = blockIdx.x;                  // 0..3
  int slice = blockIdx.y * blockDim.y + threadIdx.y;   // 0..15
  float w0 = t_cw[u], w1 = t_cw[128+u], w2 = t_cw[256+u];
  float cb = t_cb[u];
  float sc = __fmul_rn(BN_RS, t_g1[u]);
  float b1 = t_b1[u];
  float mx = -INFINITY;
  const float* P = pts + ((size_t)b*2048 + (size_t)slice*128)*3;
  for (int n = 0; n < 128; ++n){
    float y = __fadd_rn(__fadd_rn(__fmul_rn(P[n*3+0], w0), __fmul_rn(P[n*3+1], w1)),
                        __fmul_rn(P[n*3+2], w2));
    y = __fadd_rn(y, cb);
    y = __fadd_rn(__fmul_rn(y, sc), b1);
    mx = fmaxf(mx, silu_f64(y));
  }
  atomicMax(&xm_mono[b*128+u], f2mono(mx));
}

// ---------------- T-Net stage 2 (f64 accum) ----------------
__global__ void tnet2_kernel(const unsigned* __restrict__ xm_mono,
                             const float* __restrict__ d1w, const float* __restrict__ d1b,
                             const float* __restrict__ g2, const float* __restrict__ b2,
                             const float* __restrict__ d2w, const float* __restrict__ d2b,
                             float* __restrict__ T9){
  __shared__ float xs[128], x2s[128];
  int u = threadIdx.x, b = blockIdx.x;
  xs[u] = mono2f(xm_mono[b*128+u]);
  __syncthreads();
  double acc = (double)d1b[u];
  for (int v = 0; v < 128; ++v) acc += (double)xs[v] * (double)d1w[v*128+u];
  double sc = (double)__fmul_rn(BN_RS, g2[u]);
  acc = acc*sc + (double)b2[u];
  double e = exp(-acc);
  x2s[u] = (float)(acc / (1.0 + e));
  __syncthreads();
  if (u < 9){
    double t = (double)d2b[u];
    for (int v = 0; v < 128; ++v) t += (double)x2s[v] * (double)d2w[v*9+u];
    T9[b*9+u] = (float)t;
  }
}

// ---------------- pc = pts @ T (np order, no fma) + sq ----------------
__global__ void pc_kernel(const float* __restrict__ pts, const float* __restrict__ T9,
                          float4* __restrict__ pc4){
  int i = blockIdx.x*blockDim.x + threadIdx.x;   // 0..8191
  int b = i >> 11;
  const float* p = pts + (size_t)i*3;
  float x = p[0], y = p[1], z = p[2];
  const float* T = T9 + b*9;
  float px = __fadd_rn(__fadd_rn(__fmul_rn(x, T[0]), __fmul_rn(y, T[3])), __fmul_rn(z, T[6]));
  float py = __fadd_rn(__fadd_rn(__fmul_rn(x, T[1]), __fmul_rn(y, T[4])), __fmul_rn(z, T[7]));
  float pz = __fadd_rn(__fadd_rn(__fmul_rn(x, T[2]), __fmul_rn(y, T[5])), __fmul_rn(z, T[8]));
  float sq = __fadd_rn(__fadd_rn(__fmul_rn(px, px), __fmul_rn(py, py)), __fmul_rn(pz, pz));
  pc4[i] = make_float4(px, py, pz, sq);
}

// ---------------- grouping: no LDS staging (pc4 is L1/L2-resident) ----------------
__global__ __launch_bounds__(256) void group_kernel(const float4* __restrict__ pc4,
                                                    f16* __restrict__ f9){
  __shared__ int ones[4][3][32];
  __shared__ int zer [4][3][32];
  const float RAD[3] = {0.1f, 0.3f, 0.5f};
  int tid = threadIdx.x, wave = tid >> 6, lane = tid & 63;
  int bid = blockIdx.x;
  int b = bid >> 9, n0 = (bid & 511) * 4;
  const float4* src = pc4 + (size_t)b*2048;

  int n = n0 + wave;
  float4 pi = src[n];
  float xi = pi.x, yi = pi.y, zi = pi.z, sqi = pi.w;
  int c1[3] = {0,0,0}, c0[3] = {0,0,0};
  unsigned long long lt = (1ULL << lane) - 1ULL;

  for (int ch = 0; ch < 32; ++ch){
    int j = ch*64 + lane;
    float4 pj = src[j];
    float dot = __fadd_rn(__fadd_rn(__fmul_rn(xi, pj.x), __fmul_rn(yi, pj.y)),
                          __fmul_rn(zi, pj.z));
    float d2 = __fsub_rn(__fadd_rn(sqi, pj.w), __fmul_rn(2.f, dot));
    float dist = sqrtf(fmaxf(d2, 0.f));
    #pragma unroll
    for (int ri = 0; ri < 3; ++ri){
      bool in = (dist <= RAD[ri]);
      unsigned long long m = __ballot(in);
      int pc_lt = (int)__popcll(m & lt);
      if (c1[ri] < 32){
        int pos = c1[ri] + pc_lt;
        if (in && pos < 32) ones[wave][ri][pos] = j;
      }
      if (c0[ri] < 32){
        int pos = c0[ri] + (int)(lane - pc_lt);
        if (!in && pos < 32) zer[wave][ri][pos] = j;
      }
      int t1 = (int)__popcll(m);
      c1[ri] += t1;
      c0[ri] += 64 - t1;
    }
    if (c1[0] >= 32 && c1[1] >= 32 && c1[2] >= 32 &&
        c0[0] >= 32 && c0[1] >= 32 && c0[2] >= 32) break;
  }

  if (lane < 32){
    h8v va, vb;
    #pragma unroll
    for (int t = 0; t < 8; ++t){ va[t] = (f16)0.f; vb[t] = (f16)0.f; }
    #pragma unroll
    for (int ri = 0; ri < 3; ++ri){
      int cc = c1[ri] < 32 ? c1[ri] : 32;
      int sel = (lane < cc) ? ones[wave][ri][lane] : zer[wave][ri][lane - cc];
      float4 p = src[sel];
      if (ri == 0){ va[0]=(f16)p.x; va[1]=(f16)p.y; va[2]=(f16)p.z; }
      if (ri == 1){ va[3]=(f16)p.x; va[4]=(f16)p.y; va[5]=(f16)p.z; }
      if (ri == 2){ va[6]=(f16)p.x; va[7]=(f16)p.y; vb[0]=(f16)p.z; }
    }
    f16* dst = f9 + (((size_t)(b*2048 + n) * 32 + lane) << 4);
    *(h8v*)dst = va;
    *(h8v*)(dst + 8) = vb;
  }
}

// ---------------- weight prep ----------------
// 32x32 fragment pack: co = sct*32 + (lane&31), ci = t*16 + ((lane>>5)<<3) + j
__device__ __forceinline__ void pack_frag32(const float* __restrict__ src, f16* __restrict__ dst,
                                            int CO, int CI, int COr, int CIr,
                                            const float* __restrict__ g,
                                            int i0, int stride){
  int NT16 = CI >> 4;
  int total = (CO >> 5) * NT16 * 512;
  for (int x = i0; x < total; x += stride){
    int j = x & 7, lane = (x >> 3) & 63;
    int t = (x >> 9) % NT16, sct = x / (NT16 << 9);
    int co = sct*32 + (lane & 31);
    int ci = t*16 + ((lane >> 5) << 3) + j;
    float v = 0.f;
    if (co < COr && ci < CIr){
      v = src[ci*COr + co];
      if (g) v *= BN_RS * g[co];
    }
    dst[x] = (f16)v;
  }
}
// 16x16 fragment pack (blk2 only)
__device__ __forceinline__ void pack_frag16(const float* __restrict__ src, f16* __restrict__ dst,
                                            int CO, int CI, int COr, int CIr,
                                            const float* __restrict__ g,
                                            int i0, int stride){
  int NT = CI >> 5;
  int total = (CO >> 4) * NT * 512;
  for (int x = i0; x < total; x += stride){
    int j = x & 7, lane = (x >> 3) & 63;
    int t = (x >> 9) % NT, sct = x / (NT << 9);
    int co = sct*16 + (lane & 15);
    int ci = t*32 + (lane >> 4)*8 + j;
    float v = 0.f;
    if (co < COr && ci < CIr){
      v = src[ci*COr + co];
      if (g) v *= BN_RS * g[co];
    }
    dst[x] = (f16)v;
  }
}

__global__ void prep_kernel(const float* __restrict__ c1w,
                            const float* __restrict__ b0w, const float* __restrict__ b1w,
                            const float* __restrict__ b2w,
                            const float* __restrict__ c1_b, const float* __restrict__ c1_g, const float* __restrict__ c1_be,
                            const float* __restrict__ res_b,
                            const float* __restrict__ b0_b, const float* __restrict__ b0_g, const float* __restrict__ b0_be,
                            const float* __restrict__ b1_b, const float* __restrict__ b1_g, const float* __restrict__ b1_be,
                            const float* __restrict__ b2_b, const float* __restrict__ b2_g, const float* __restrict__ b2_be,
                            f16* __restrict__ c1F, f16* __restrict__ b1F, f16* __restrict__ b2F,
                            float* __restrict__ bs1, float* __restrict__ bs0,
                            float* __restrict__ bsb1, float* __restrict__ bsb2){
  int i0 = blockIdx.x*blockDim.x + threadIdx.x;
  int stride = gridDim.x*blockDim.x;
  pack_frag32(c1w,  c1F,  512,  32, 512,   9, c1_g, i0, stride);
  pack_frag32(b1w,  b1F,  256, 512, 256, 512, b1_g, i0, stride);
  pack_frag16(b2w,  b2F,  176, 256, 170, 256, b2_g, i0, stride);
  for (int x = i0; x < 512; x += stride){
    bs1[x] = c1_b[x]*(BN_RS*c1_g[x]) + c1_be[x];
    float s = b0_b[x];
    for (int m = 0; m < 512; ++m) s = fmaf(res_b[m], b0w[m*512 + x], s);
    bs0[x] = s*(BN_RS*b0_g[x]) + b0_be[x];
  }
  for (int x = i0; x < 256; x += stride) bsb1[x] = b1_b[x]*(BN_RS*b1_g[x]) + b1_be[x];
  for (int x = i0; x < 176; x += stride)
    bsb2[x] = (x < 170) ? b2_b[x]*(BN_RS*b2_g[x]) + b2_be[x] : 0.f;
}

// ---------------- tiled compose (I+R)@W0, BN-fold, frag32-packed f16 out ----------------
__global__ __launch_bounds__(256) void composeb0_kernel(const float* __restrict__ resw,
                                                        const float* __restrict__ b0w,
                                                        const float* __restrict__ b0_g,
                                                        f16* __restrict__ b0C){
  __shared__ float Rt[64][129];
  __shared__ float Wt[128][17];
  const int tid = threadIdx.x;
  const int co0 = (blockIdx.x & 31) * 16;
  const int ci0 = (blockIdx.x >> 5) * 64;
  const int r  = tid >> 2;
  const int cq = tid & 3;
  float acc[4] = {0.f, 0.f, 0.f, 0.f};

  for (int mc = 0; mc < 512; mc += 128){
    {
      int row = tid >> 2, mb = (tid & 3) * 32;
      const float* src = resw + (size_t)(ci0 + row)*512 + mc + mb;
      #pragma unroll
      for (int i = 0; i < 8; ++i){
        float4 v = *(const float4*)(src + i*4);
        Rt[row][mb + i*4 + 0] = v.x; Rt[row][mb + i*4 + 1] = v.y;
        Rt[row][mb + i*4 + 2] = v.z; Rt[row][mb + i*4 + 3] = v.w;
      }
    }
    {
      int m = tid >> 1, c8 = (tid & 1) * 8;
      const float* src = b0w + (size_t)(mc + m)*512 + co0 + c8;
      float4 v0 = *(const float4*)(src);
      float4 v1 = *(const float4*)(src + 4);
      Wt[m][c8+0] = v0.x; Wt[m][c8+1] = v0.y; Wt[m][c8+2] = v0.z; Wt[m][c8+3] = v0.w;
      Wt[m][c8+4] = v1.x; Wt[m][c8+5] = v1.y; Wt[m][c8+6] = v1.z; Wt[m][c8+7] = v1.w;
    }
    __syncthreads();
    #pragma unroll 8
    for (int m = 0; m < 128; ++m){
      float rv = Rt[r][m];
      #pragma unroll
      for (int i = 0; i < 4; ++i)
        acc[i] = fmaf(rv, Wt[m][cq*4 + i], acc[i]);
    }
    __syncthreads();
  }
  int ci = ci0 + r;
  #pragma unroll
  for (int i = 0; i < 4; ++i){
    int co = co0 + cq*4 + i;
    float s = acc[i] + b0w[(size_t)ci*512 + co];   // e_ci term of (I+R)
    s *= BN_RS * b0_g[co];
    int sct = co >> 5, t = ci >> 4;
    int lane = (co & 31) | (((ci >> 3) & 1) << 5);
    int j = ci & 7;
    b0C[((size_t)(sct*32 + t)*64 + lane)*8 + j] = (f16)s;
  }
}

// ---------------- MLP (64-row tiles, 32x32 MFMA, 2 blocks/CU cap) ----------------
// act tile: 64 rows x 512 f16, stride 1024 B, XOR-swizzled by ((row&7)<<4)
__device__ __forceinline__ int swzb(int row, int c){
  return (row*1024 + c*2) ^ ((row & 7) << 4);
}

// 32x32 register-streamed layer, 2 row-tiles: w shared across row-tiles.
template<int NT16, int NCT>
__device__ __forceinline__ void mm32x2(const char* actc, const f16* __restrict__ WF,
                                       int sct0, int lane, f32x16 (&acc)[2][NCT]){
  const int ln = lane & 31, hi = lane >> 5;
  const int xr = (ln & 7) << 4;
  #pragma unroll
  for (int t = 0; t < NT16; ++t){
    int koff = (t*32 + (hi << 4)) ^ xr;
    h8v a0 = *(const h8v*)(actc + ln*1024 + koff);
    h8v a1 = *(const h8v*)(actc + (32 + ln)*1024 + koff);
    #pragma unroll
    for (int ct = 0; ct < NCT; ++ct){
      h8v w = *(const h8v*)&WF[((size_t)((sct0 + ct)*NT16 + t)*64 + lane)*8];
      acc[0][ct] = __builtin_amdgcn_mfma_f32_32x32x16_f16(w, a0, acc[0][ct], 0, 0, 0);
      acc[1][ct] = __builtin_amdgcn_mfma_f32_32x32x16_f16(w, a1, acc[1][ct], 0, 0, 0);
    }
  }
}

// 32x32 silu epilogue, 2 row-tiles: reg r: ch_local=(r&3)+8*(r>>2)+4*hi, row=mt*32+ln.
template<int NCT>
__device__ __forceinline__ void epi32x2(char* outc, int co0, const float* __restrict__ bias,
                                        int lane, f32x16 (&acc)[2][NCT]){
  const int ln = lane & 31, hi = lane >> 5;
  #pragma unroll
  for (int ct = 0; ct < NCT; ++ct){
    #pragma unroll
    for (int q = 0; q < 4; ++q){
      int ch = co0 + ct*32 + q*8 + hi*4;
      float4 b4 = *(const float4*)(bias + ch);
      #pragma unroll
      for (int mt = 0; mt < 2; ++mt){
        int row = mt*32 + ln;
        *(h4v*)(outc + swzb(row, ch)) = pkrtz4(
            silu_fast(acc[mt][ct][q*4+0] + b4.x),
            silu_fast(acc[mt][ct][q*4+1] + b4.y),
            silu_fast(acc[mt][ct][q*4+2] + b4.z),
            silu_fast(acc[mt][ct][q*4+3] + b4.w));
      }
    }
  }
}

__global__ __launch_bounds__(512, 2) void mlp_kernel(
    const f16* __restrict__ f9,
    const f16* __restrict__ c1F, const f16* __restrict__ b0C,
    const f16* __restrict__ b1F, const f16* __restrict__ b2F,
    const float* __restrict__ bs1, const float* __restrict__ bs0,
    const float* __restrict__ bsb1, const float* __restrict__ bsb2,
    unsigned* __restrict__ outmax){
  __shared__ __align__(16) f16 bufA[64*512];      // ping-pong act buffers (64 KiB each)
  __shared__ __align__(16) f16 bufB[64*512];
  char* A = (char*)bufA;
  char* B = (char*)bufB;
  const int tid  = threadIdx.x;
  const int wave = tid >> 6, lane = tid & 63;
  const int ln = lane & 31, hi = lane >> 5;
  const int lrow = lane & 15, lkg = lane >> 4;    // 16x16 path (blk2)
  const int bid = blockIdx.x;
  const int b = bid >> 10, k = (bid >> 5) & 31, n0 = (bid & 31) << 6;

  // stage f9 rows [64][32] into bufA front region (cols 16..31 zero)
  if (tid < 256){
    int row = tid >> 2, part = tid & 3;
    h8v v;
    if (part < 2){
      const f16* src = f9 + (((size_t)(b*2048 + n0 + row) * 32 + k) << 4) + part*8;
      v = *(const h8v*)src;
    } else {
      #pragma unroll
      for (int t = 0; t < 8; ++t) v[t] = (f16)0.f;
    }
    *(h8v*)&bufA[row*32 + part*8] = v;
  }
  __syncthreads();

  const f32x16 zf16 = {0.f,0.f,0.f,0.f,0.f,0.f,0.f,0.f,0.f,0.f,0.f,0.f,0.f,0.f,0.f,0.f};
  f32x16 acc[2][2];

  // ---- layer 1: Ci=32 (padded 9), Co=512, A(front [64][32]) -> B ----
  acc[0][0] = zf16; acc[0][1] = zf16; acc[1][0] = zf16; acc[1][1] = zf16;
  #pragma unroll
  for (int t = 0; t < 2; ++t){
    h8v a0 = *(const h8v*)(A + ln*64 + t*32 + hi*16);        // front region, no swizzle
    h8v a1 = *(const h8v*)(A + (32 + ln)*64 + t*32 + hi*16);
    #pragma unroll
    for (int ct = 0; ct < 2; ++ct){
      h8v w = *(const h8v*)&c1F[((size_t)((wave*2 + ct)*2 + t)*64 + lane)*8];
      acc[0][ct] = __builtin_amdgcn_mfma_f32_32x32x16_f16(w, a0, acc[0][ct], 0, 0, 0);
      acc[1][ct] = __builtin_amdgcn_mfma_f32_32x32x16_f16(w, a1, acc[1][ct], 0, 0, 0);
    }
  }
  epi32x2<2>(B, wave*64, bs1, lane, acc);
  __syncthreads();

  // ---- blk0': composed (I+R)@W0, 512 -> 512, B -> A ----
  acc[0][0] = zf16; acc[0][1] = zf16; acc[1][0] = zf16; acc[1][1] = zf16;
  mm32x2<32, 2>(B, b0C, wave*2, lane, acc);
  epi32x2<2>(A, wave*64, bs0, lane, acc);
  __syncthreads();

  // ---- blk1: 512 -> 256, A -> B (cols 0..255) ----
  f32x16 acc1[2][1];
  acc1[0][0] = zf16; acc1[1][0] = zf16;
  mm32x2<32, 1>(A, b1F, wave, lane, acc1);
  epi32x2<1>(B, wave*32, bsb1, lane, acc1);
  __syncthreads();

  // ---- blk2: 256 -> 170 (pad 176), 16x16 path, B as A-operand, + row-max + atomic ----
  const f32x4 zf = {0.f, 0.f, 0.f, 0.f};
  f32x4 acc3[4][2];
  #pragma unroll
  for (int mt = 0; mt < 4; ++mt){ acc3[mt][0] = zf; acc3[mt][1] = zf; }
  {
    const int xr = (lrow & 7) << 4;
    const bool has2 = wave < 3;                    // wave+8 < 11
    #pragma unroll
    for (int t = 0; t < 8; ++t){
      h8v a[4];
      int koff = ((t*4 + lkg) << 4) ^ xr;
      #pragma unroll
      for (int mt = 0; mt < 4; ++mt)
        a[mt] = *(const h8v*)(B + (mt*16 + lrow)*1024 + koff);
      {
        h8v w = *(const h8v*)&b2F[((size_t)(wave*8 + t)*64 + lane)*8];
        #pragma unroll
        for (int mt = 0; mt < 4; ++mt)
          acc3[mt][0] = __builtin_amdgcn_mfma_f32_16x16x32_f16(a[mt], w, acc3[mt][0], 0, 0, 0);
      }
      if (has2){
        h8v w = *(const h8v*)&b2F[((size_t)((wave + 8)*8 + t)*64 + lane)*8];
        #pragma unroll
        for (int mt = 0; mt < 4; ++mt)
          acc3[mt][1] = __builtin_amdgcn_mfma_f32_16x16x32_f16(a[mt], w, acc3[mt][1], 0, 0, 0);
      }
    }
    #pragma unroll
    for (int t = 0; t < 2; ++t){
      if (t == 1 && !has2) break;
      int c = ((t == 0) ? wave : wave + 8)*16 + lrow;
      if (c < 170){
        float bb = bsb2[c];
        float mx = -INFINITY;
        #pragma unroll
        for (int mt = 0; mt < 4; ++mt)
          #pragma unroll
          for (int rg = 0; rg < 4; ++rg)
            mx = fmaxf(mx, silu_fast(acc3[mt][t][rg] + bb));
        mx = fmaxf(mx, __shfl_xor(mx, 16));
        mx = fmaxf(mx, __shfl_xor(mx, 32));
        if (lkg == 0)
          atomicMax(&outmax[b*5440 + k*170 + c], f2mono(mx));
      }
    }
  }
}

__global__ void finalize_kernel(const unsigned* __restrict__ m, float* __restrict__ out, int n){
  int i = blockIdx.x*blockDim.x + threadIdx.x;
  if (i < n) out[i] = mono2f(m[i]);
}

// ---------------- launch ----------------
extern "C" void kernel_launch(void* const* d_in, const int* in_sizes, int n_in,
                              void* d_out, int out_size, void* d_ws, size_t ws_size,
                              hipStream_t stream){
  const float* pts    = (const float*)d_in[0];
  const float* t_cw   = (const float*)d_in[1];
  const float* t_cb   = (const float*)d_in[2];
  const float* t_g1   = (const float*)d_in[3];
  const float* t_b1   = (const float*)d_in[4];
  const float* t_d1w  = (const float*)d_in[5];
  const float* t_d1b  = (const float*)d_in[6];
  const float* t_g2   = (const float*)d_in[7];
  const float* t_b2   = (const float*)d_in[8];
  const float* t_d2w  = (const float*)d_in[9];
  const float* t_d2b  = (const float*)d_in[10];
  const float* c1_w   = (const float*)d_in[11];
  const float* c1_b   = (const float*)d_in[12];
  const float* c1_g   = (const float*)d_in[13];
  const float* c1_be  = (const float*)d_in[14];
  const float* res_w  = (const float*)d_in[15];
  const float* res_b  = (const float*)d_in[16];
  const float* b0_w   = (const float*)d_in[17];
  const float* b0_b   = (const float*)d_in[18];
  const float* b0_g   = (const float*)d_in[19];
  const float* b0_be  = (const float*)d_in[20];
  const float* b1_w   = (const float*)d_in[21];
  const float* b1_b   = (const float*)d_in[22];
  const float* b1_g   = (const float*)d_in[23];
  const float* b1_be  = (const float*)d_in[24];
  const float* b2_w   = (const float*)d_in[25];
  const float* b2_b   = (const float*)d_in[26];
  const float* b2_g   = (const float*)d_in[27];
  const float* b2_be  = (const float*)d_in[28];

  char* ws = (char*)d_ws;
  float*    T9   = (float*)(ws + OFF_T9);
  unsigned* XM   = (unsigned*)(ws + OFF_XM);
  float4*   PC4  = (float4*)(ws + OFF_PC4);
  unsigned* OUTM = (unsigned*)(ws + OFF_OUT);
  f16* C1F  = (f16*)(ws + OFF_C1T);
  f16* B0C  = (f16*)(ws + OFF_B0C);
  f16* B1F  = (f16*)(ws + OFF_B1T);
  f16* B2F  = (f16*)(ws + OFF_B2T);
  float* BS1  = (float*)(ws + OFF_BS1);
  float* BS0  = (float*)(ws + OFF_BS0);
  float* BSB1 = (float*)(ws + OFF_BSB1);
  float* BSB2 = (float*)(ws + OFF_BSB2);
  f16* F9   = (f16*)(ws + OFF_F9);

  hipMemsetAsync(ws + OFF_XM, 0, 4*128*4, stream);
  hipMemsetAsync(ws + OFF_OUT, 0, 21760*4, stream);

  prep_kernel<<<512, 256, 0, stream>>>(c1_w, b0_w, b1_w, b2_w,
                                       c1_b, c1_g, c1_be, res_b,
                                       b0_b, b0_g, b0_be,
                                       b1_b, b1_g, b1_be,
                                       b2_b, b2_g, b2_be,
                                       C1F, B1F, B2F,
                                       BS1, BS0, BSB1, BSB2);
  composeb0_kernel<<<256, 256, 0, stream>>>(res_w, b0_w, b0_g, B0C);
  tnet1_kernel<<<dim3(4,4), dim3(128,4), 0, stream>>>(pts, t_cw, t_cb, t_g1, t_b1, XM);
  tnet2_kernel<<<4, 128, 0, stream>>>(XM, t_d1w, t_d1b, t_g2, t_b2, t_d2w, t_d2b, T9);
  pc_kernel<<<32, 256, 0, stream>>>(pts, T9, PC4);
  group_kernel<<<2048, 256, 0, stream>>>(PC4, F9);
  mlp_kernel<<<4096, 512, 0, stream>>>(F9, C1F, B0C, B1F, B2F,
                                       BS1, BS0, BSB1, BSB2, OUTM);
  finalize_kernel<<<(out_size + 255)/256, 256, 0, stream>>>(OUTM, (float*)d_out, out_size);
}

// Round 22
// 427.110 us; speedup vs baseline: 1.0921x; 1.0633x over previous
//
#include <hip/hip_runtime.h>
#include <math.h>

#define BN_RS 0.9995003746877732f

typedef unsigned short u16;
typedef _Float16 f16;
typedef __attribute__((ext_vector_type(8))) _Float16 h8v;     // 8 f16 (A/B frag)
typedef __attribute__((ext_vector_type(4))) _Float16 h4v;     // packed 4 f16 (8B)
typedef __attribute__((ext_vector_type(2))) __fp16 fp16x2;    // cvt_pkrtz native type
typedef __attribute__((ext_vector_type(4))) float f32x4;      // C/D frag

// ---------------- helpers ----------------
__device__ __forceinline__ unsigned f2mono(float f){
  unsigned u = __float_as_uint(f);
  return (u & 0x80000000u) ? ~u : (u | 0x80000000u);
}
__device__ __forceinline__ float mono2f(unsigned m){
  unsigned u = (m & 0x80000000u) ? (m & 0x7FFFFFFFu) : ~m;
  return __uint_as_float(u);
}
__device__ __forceinline__ float silu_fast(float x){
  float e = __expf(-x);
  return x * __builtin_amdgcn_rcpf(1.f + e);      // v_rcp_f32: 1-ulp
}
__device__ __forceinline__ float silu_f64(float x){
  double e = exp(-(double)x);
  return (float)((double)x / (1.0 + e));
}
// pack 4 f32 -> 4 f16 with 2 v_cvt_pkrtz_f16_f32 instructions
__device__ __forceinline__ h4v pkrtz4(float a, float b, float c, float d){
  fp16x2 lo = __builtin_amdgcn_cvt_pkrtz(a, b);
  fp16x2 hi = __builtin_amdgcn_cvt_pkrtz(c, d);
  unsigned lu = __builtin_bit_cast(unsigned, lo);
  unsigned hu = __builtin_bit_cast(unsigned, hi);
  unsigned long long packed = ((unsigned long long)hu << 32) | lu;
  return __builtin_bit_cast(h4v, packed);
}

// ---------------- ws layout (bytes) ----------------
constexpr size_t OFF_T9   = 0;         //  4*9*4
constexpr size_t OFF_XM   = 1024;      //  4*128*4 (mono uints)
constexpr size_t OFF_PC4  = 4096;      //  8192*16
constexpr size_t OFF_OUT  = 139264;    //  21760*4
constexpr size_t OFF_C1T  = 227328;    //  512*32*2   (frag16-packed, BN-folded)
constexpr size_t OFF_B0C  = 262144;    //  512*512*2  (frag16-packed, composed (I+R)@W0)
constexpr size_t OFF_B1T  = 1310720;   //  256*512*2  (frag16-packed, BN-folded)
constexpr size_t OFF_B2T  = 1572864;   //  176*256*2  (frag16-packed, BN-folded)
constexpr size_t OFF_BS1  = 1662976;   //  512*4 bias (BN-folded)
constexpr size_t OFF_BS0  = 1667072;   //  512*4 (composed)
constexpr size_t OFF_BSB1 = 1669120;   //  256*4
constexpr size_t OFF_BSB2 = 1670144;   //  176*4  (ends 1670848 < OFF_F9)
constexpr size_t OFF_F9   = 1703936;   //  8192*32*16*2

// ---------------- T-Net stage 1 ----------------
__global__ void tnet1_kernel(const float* __restrict__ pts, const float* __restrict__ t_cw,
                             const float* __restrict__ t_cb, const float* __restrict__ t_g1,
                             const float* __restrict__ t_b1, unsigned* __restrict__ xm_mono){
  int u = threadIdx.x;                 // 0..127
  int b = blockIdx.x;                  // 0..3
  int slice = blockIdx.y * blockDim.y + threadIdx.y;   // 0..15
  float w0 = t_cw[u], w1 = t_cw[128+u], w2 = t_cw[256+u];
  float cb = t_cb[u];
  float sc = __fmul_rn(BN_RS, t_g1[u]);
  float b1 = t_b1[u];
  float mx = -INFINITY;
  const float* P = pts + ((size_t)b*2048 + (size_t)slice*128)*3;
  for (int n = 0; n < 128; ++n){
    float y = __fadd_rn(__fadd_rn(__fmul_rn(P[n*3+0], w0), __fmul_rn(P[n*3+1], w1)),
                        __fmul_rn(P[n*3+2], w2));
    y = __fadd_rn(y, cb);
    y = __fadd_rn(__fmul_rn(y, sc), b1);
    mx = fmaxf(mx, silu_f64(y));
  }
  atomicMax(&xm_mono[b*128+u], f2mono(mx));
}

// ---------------- T-Net stage 2 (f64 accum) ----------------
__global__ void tnet2_kernel(const unsigned* __restrict__ xm_mono,
                             const float* __restrict__ d1w, const float* __restrict__ d1b,
                             const float* __restrict__ g2, const float* __restrict__ b2,
                             const float* __restrict__ d2w, const float* __restrict__ d2b,
                             float* __restrict__ T9){
  __shared__ float xs[128], x2s[128];
  int u = threadIdx.x, b = blockIdx.x;
  xs[u] = mono2f(xm_mono[b*128+u]);
  __syncthreads();
  double acc = (double)d1b[u];
  for (int v = 0; v < 128; ++v) acc += (double)xs[v] * (double)d1w[v*128+u];
  double sc = (double)__fmul_rn(BN_RS, g2[u]);
  acc = acc*sc + (double)b2[u];
  double e = exp(-acc);
  x2s[u] = (float)(acc / (1.0 + e));
  __syncthreads();
  if (u < 9){
    double t = (double)d2b[u];
    for (int v = 0; v < 128; ++v) t += (double)x2s[v] * (double)d2w[v*9+u];
    T9[b*9+u] = (float)t;
  }
}

// ---------------- pc = pts @ T (np order, no fma) + sq ----------------
__global__ void pc_kernel(const float* __restrict__ pts, const float* __restrict__ T9,
                          float4* __restrict__ pc4){
  int i = blockIdx.x*blockDim.x + threadIdx.x;   // 0..8191
  int b = i >> 11;
  const float* p = pts + (size_t)i*3;
  float x = p[0], y = p[1], z = p[2];
  const float* T = T9 + b*9;
  float px = __fadd_rn(__fadd_rn(__fmul_rn(x, T[0]), __fmul_rn(y, T[3])), __fmul_rn(z, T[6]));
  float py = __fadd_rn(__fadd_rn(__fmul_rn(x, T[1]), __fmul_rn(y, T[4])), __fmul_rn(z, T[7]));
  float pz = __fadd_rn(__fadd_rn(__fmul_rn(x, T[2]), __fmul_rn(y, T[5])), __fmul_rn(z, T[8]));
  float sq = __fadd_rn(__fadd_rn(__fmul_rn(px, px), __fmul_rn(py, py)), __fmul_rn(pz, pz));
  pc4[i] = make_float4(px, py, pz, sq);
}

// ---------------- grouping: no LDS staging (pc4 is L1/L2-resident) ----------------
__global__ __launch_bounds__(256) void group_kernel(const float4* __restrict__ pc4,
                                                    f16* __restrict__ f9){
  __shared__ int ones[4][3][32];
  __shared__ int zer [4][3][32];
  const float RAD[3] = {0.1f, 0.3f, 0.5f};
  int tid = threadIdx.x, wave = tid >> 6, lane = tid & 63;
  int bid = blockIdx.x;
  int b = bid >> 9, n0 = (bid & 511) * 4;
  const float4* src = pc4 + (size_t)b*2048;

  int n = n0 + wave;
  float4 pi = src[n];
  float xi = pi.x, yi = pi.y, zi = pi.z, sqi = pi.w;
  int c1[3] = {0,0,0}, c0[3] = {0,0,0};
  unsigned long long lt = (1ULL << lane) - 1ULL;

  for (int ch = 0; ch < 32; ++ch){
    int j = ch*64 + lane;
    float4 pj = src[j];
    float dot = __fadd_rn(__fadd_rn(__fmul_rn(xi, pj.x), __fmul_rn(yi, pj.y)),
                          __fmul_rn(zi, pj.z));
    float d2 = __fsub_rn(__fadd_rn(sqi, pj.w), __fmul_rn(2.f, dot));
    float dist = sqrtf(fmaxf(d2, 0.f));
    #pragma unroll
    for (int ri = 0; ri < 3; ++ri){
      bool in = (dist <= RAD[ri]);
      unsigned long long m = __ballot(in);
      int pc_lt = (int)__popcll(m & lt);
      if (c1[ri] < 32){
        int pos = c1[ri] + pc_lt;
        if (in && pos < 32) ones[wave][ri][pos] = j;
      }
      if (c0[ri] < 32){
        int pos = c0[ri] + (int)(lane - pc_lt);
        if (!in && pos < 32) zer[wave][ri][pos] = j;
      }
      int t1 = (int)__popcll(m);
      c1[ri] += t1;
      c0[ri] += 64 - t1;
    }
    if (c1[0] >= 32 && c1[1] >= 32 && c1[2] >= 32 &&
        c0[0] >= 32 && c0[1] >= 32 && c0[2] >= 32) break;
  }

  if (lane < 32){
    h8v va, vb;
    #pragma unroll
    for (int t = 0; t < 8; ++t){ va[t] = (f16)0.f; vb[t] = (f16)0.f; }
    #pragma unroll
    for (int ri = 0; ri < 3; ++ri){
      int cc = c1[ri] < 32 ? c1[ri] : 32;
      int sel = (lane < cc) ? ones[wave][ri][lane] : zer[wave][ri][lane - cc];
      float4 p = src[sel];
      if (ri == 0){ va[0]=(f16)p.x; va[1]=(f16)p.y; va[2]=(f16)p.z; }
      if (ri == 1){ va[3]=(f16)p.x; va[4]=(f16)p.y; va[5]=(f16)p.z; }
      if (ri == 2){ va[6]=(f16)p.x; va[7]=(f16)p.y; vb[0]=(f16)p.z; }
    }
    f16* dst = f9 + (((size_t)(b*2048 + n) * 32 + lane) << 4);
    *(h8v*)dst = va;
    *(h8v*)(dst + 8) = vb;
  }
}

// ---------------- weight prep: frag16 pack + BN fold ----------------
__device__ __forceinline__ void pack_frag(const float* __restrict__ src, f16* __restrict__ dst,
                                          int CO, int CI, int COr, int CIr,
                                          const float* __restrict__ g,
                                          int i0, int stride){
  int NT = CI >> 5;
  int total = (CO >> 4) * NT * 512;
  for (int x = i0; x < total; x += stride){
    int j = x & 7, lane = (x >> 3) & 63;
    int t = (x >> 9) % NT, sct = x / (NT << 9);
    int co = sct*16 + (lane & 15);
    int ci = t*32 + (lane >> 4)*8 + j;
    float v = 0.f;
    if (co < COr && ci < CIr){
      v = src[ci*COr + co];
      if (g) v *= BN_RS * g[co];
    }
    dst[x] = (f16)v;
  }
}

__global__ void prep_kernel(const float* __restrict__ c1w,
                            const float* __restrict__ b0w, const float* __restrict__ b1w,
                            const float* __restrict__ b2w,
                            const float* __restrict__ c1_b, const float* __restrict__ c1_g, const float* __restrict__ c1_be,
                            const float* __restrict__ res_b,
                            const float* __restrict__ b0_b, const float* __restrict__ b0_g, const float* __restrict__ b0_be,
                            const float* __restrict__ b1_b, const float* __restrict__ b1_g, const float* __restrict__ b1_be,
                            const float* __restrict__ b2_b, const float* __restrict__ b2_g, const float* __restrict__ b2_be,
                            f16* __restrict__ c1F, f16* __restrict__ b1F, f16* __restrict__ b2F,
                            float* __restrict__ bs1, float* __restrict__ bs0,
                            float* __restrict__ bsb1, float* __restrict__ bsb2){
  int i0 = blockIdx.x*blockDim.x + threadIdx.x;
  int stride = gridDim.x*blockDim.x;
  pack_frag(c1w,  c1F,  512,  32, 512,   9, c1_g, i0, stride);
  pack_frag(b1w,  b1F,  256, 512, 256, 512, b1_g, i0, stride);
  pack_frag(b2w,  b2F,  176, 256, 170, 256, b2_g, i0, stride);
  for (int x = i0; x < 512; x += stride){
    bs1[x] = c1_b[x]*(BN_RS*c1_g[x]) + c1_be[x];
    float s = b0_b[x];
    for (int m = 0; m < 512; ++m) s = fmaf(res_b[m], b0w[m*512 + x], s);
    bs0[x] = s*(BN_RS*b0_g[x]) + b0_be[x];
  }
  for (int x = i0; x < 256; x += stride) bsb1[x] = b1_b[x]*(BN_RS*b1_g[x]) + b1_be[x];
  for (int x = i0; x < 176; x += stride)
    bsb2[x] = (x < 170) ? b2_b[x]*(BN_RS*b2_g[x]) + b2_be[x] : 0.f;
}

// ---------------- tiled compose (I+R)@W0, BN-fold, frag16-packed f16 out ----------------
__global__ __launch_bounds__(256) void composeb0_kernel(const float* __restrict__ resw,
                                                        const float* __restrict__ b0w,
                                                        const float* __restrict__ b0_g,
                                                        f16* __restrict__ b0C){
  __shared__ float Rt[64][129];
  __shared__ float Wt[128][17];
  const int tid = threadIdx.x;
  const int co0 = (blockIdx.x & 31) * 16;
  const int ci0 = (blockIdx.x >> 5) * 64;
  const int r  = tid >> 2;
  const int cq = tid & 3;
  float acc[4] = {0.f, 0.f, 0.f, 0.f};

  for (int mc = 0; mc < 512; mc += 128){
    {
      int row = tid >> 2, mb = (tid & 3) * 32;
      const float* src = resw + (size_t)(ci0 + row)*512 + mc + mb;
      #pragma unroll
      for (int i = 0; i < 8; ++i){
        float4 v = *(const float4*)(src + i*4);
        Rt[row][mb + i*4 + 0] = v.x; Rt[row][mb + i*4 + 1] = v.y;
        Rt[row][mb + i*4 + 2] = v.z; Rt[row][mb + i*4 + 3] = v.w;
      }
    }
    {
      int m = tid >> 1, c8 = (tid & 1) * 8;
      const float* src = b0w + (size_t)(mc + m)*512 + co0 + c8;
      float4 v0 = *(const float4*)(src);
      float4 v1 = *(const float4*)(src + 4);
      Wt[m][c8+0] = v0.x; Wt[m][c8+1] = v0.y; Wt[m][c8+2] = v0.z; Wt[m][c8+3] = v0.w;
      Wt[m][c8+4] = v1.x; Wt[m][c8+5] = v1.y; Wt[m][c8+6] = v1.z; Wt[m][c8+7] = v1.w;
    }
    __syncthreads();
    #pragma unroll 8
    for (int m = 0; m < 128; ++m){
      float rv = Rt[r][m];
      #pragma unroll
      for (int i = 0; i < 4; ++i)
        acc[i] = fmaf(rv, Wt[m][cq*4 + i], acc[i]);
    }
    __syncthreads();
  }
  int ci = ci0 + r;
  #pragma unroll
  for (int i = 0; i < 4; ++i){
    int co = co0 + cq*4 + i;
    float s = acc[i] + b0w[(size_t)ci*512 + co];   // e_ci term of (I+R)
    s *= BN_RS * b0_g[co];
    int sct = co >> 4, t = ci >> 5;
    int lane = (co & 15) | (((ci >> 3) & 3) << 4);
    int j = ci & 7;
    b0C[((size_t)(sct*16 + t)*64 + lane)*8 + j] = (f16)s;
  }
}

// ---------------- MLP (64-row tiles, 16x16 MFMA, ping-pong; R18 structure) ----------------
// act tile: 64 rows x 512 f16, stride 1024 B, XOR-swizzled by ((row&7)<<4)
__device__ __forceinline__ int swzb(int row, int c){
  return (row*1024 + c*2) ^ ((row & 7) << 4);
}

// register-streamed layer: acts from LDS, weights straight from global (frag-packed,
// coalesced lane*16), MFMAs; NO barriers inside — compiler pipelines freely.
template<int NT, int NCT>
__device__ __forceinline__ void mm_stream(const char* actc, const f16* __restrict__ WF,
                                          int sct0, int lane, int lrow, int lkg,
                                          f32x4 (&acc)[4][NCT]){
  const int xr = (lrow & 7) << 4;
  #pragma unroll
  for (int t = 0; t < NT; ++t){
    h8v a[4];
    int koff = ((t*4 + lkg) << 4) ^ xr;
    #pragma unroll
    for (int mt = 0; mt < 4; ++mt)
      a[mt] = *(const h8v*)(actc + (mt*16 + lrow)*1024 + koff);
    #pragma unroll
    for (int ct = 0; ct < NCT; ++ct){
      h8v w = *(const h8v*)&WF[((size_t)((sct0 + ct)*NT + t)*64 + lane)*8];
      #pragma unroll
      for (int mt = 0; mt < 4; ++mt)
        acc[mt][ct] = __builtin_amdgcn_mfma_f32_16x16x32_f16(w, a[mt], acc[mt][ct], 0, 0, 0);
    }
  }
}

// silu epilogue: v = silu(acc + bias), rcp-silu + pkrtz, packed 8B stores
template<int NCT>
__device__ __forceinline__ void epi_silu(char* outc, int co0, const float* __restrict__ bias,
                                         int lrow, int lkg, f32x4 (&acc)[4][NCT]){
  #pragma unroll
  for (int ct = 0; ct < NCT; ++ct){
    int co = co0 + ct*16 + lkg*4;
    float4 b4 = *(const float4*)(bias + co);
    #pragma unroll
    for (int mt = 0; mt < 4; ++mt){
      int r = mt*16 + lrow;
      *(h4v*)(outc + swzb(r, co)) = pkrtz4(
          silu_fast(acc[mt][ct][0] + b4.x),
          silu_fast(acc[mt][ct][1] + b4.y),
          silu_fast(acc[mt][ct][2] + b4.z),
          silu_fast(acc[mt][ct][3] + b4.w));
    }
  }
}

__global__ __launch_bounds__(512, 2) void mlp_kernel(
    const f16* __restrict__ f9,
    const f16* __restrict__ c1F, const f16* __restrict__ b0C,
    const f16* __restrict__ b1F, const f16* __restrict__ b2F,
    const float* __restrict__ bs1, const float* __restrict__ bs0,
    const float* __restrict__ bsb1, const float* __restrict__ bsb2,
    unsigned* __restrict__ outmax){
  __shared__ __align__(16) f16 bufA[64*512];      // ping-pong act buffers (64 KiB each)
  __shared__ __align__(16) f16 bufB[64*512];
  char* A = (char*)bufA;
  char* B = (char*)bufB;
  const int tid  = threadIdx.x;
  const int wave = tid >> 6, lane = tid & 63;
  const int lrow = lane & 15, lkg = lane >> 4;
  const int bid = blockIdx.x;
  const int b = bid >> 10, k = (bid >> 5) & 31, n0 = (bid & 31) << 6;

  // stage f9 rows [64][32] into bufA front region (cols 16..31 zero)
  if (tid < 256){
    int row = tid >> 2, part = tid & 3;
    h8v v;
    if (part < 2){
      const f16* src = f9 + (((size_t)(b*2048 + n0 + row) * 32 + k) << 4) + part*8;
      v = *(const h8v*)src;
    } else {
      #pragma unroll
      for (int t = 0; t < 8; ++t) v[t] = (f16)0.f;
    }
    *(h8v*)&bufA[row*32 + part*8] = v;
  }
  __syncthreads();

  const f32x4 zf = {0.f, 0.f, 0.f, 0.f};
  f32x4 acc4[4][4];

  // ---- layer 1: Ci=32 (padded 9), Co=512, A(front) -> B ----
  #pragma unroll
  for (int mt = 0; mt < 4; ++mt)
    #pragma unroll
    for (int ct = 0; ct < 4; ++ct) acc4[mt][ct] = zf;
  {
    h8v a[4];
    #pragma unroll
    for (int mt = 0; mt < 4; ++mt)
      a[mt] = *(const h8v*)(A + (mt*16 + lrow)*64 + lkg*16);
    #pragma unroll
    for (int ct = 0; ct < 4; ++ct){
      h8v w = *(const h8v*)&c1F[((size_t)(wave*4 + ct)*64 + lane)*8];
      #pragma unroll
      for (int mt = 0; mt < 4; ++mt)
        acc4[mt][ct] = __builtin_amdgcn_mfma_f32_16x16x32_f16(w, a[mt], acc4[mt][ct], 0, 0, 0);
    }
  }
  epi_silu<4>(B, wave*64, bs1, lrow, lkg, acc4);
  __syncthreads();

  // ---- blk0': composed (I+R)@W0, 512 -> 512, B -> A ----
  #pragma unroll
  for (int mt = 0; mt < 4; ++mt)
    #pragma unroll
    for (int ct = 0; ct < 4; ++ct) acc4[mt][ct] = zf;
  mm_stream<16, 4>(B, b0C, wave*4, lane, lrow, lkg, acc4);
  epi_silu<4>(A, wave*64, bs0, lrow, lkg, acc4);
  __syncthreads();

  // ---- blk1: 512 -> 256, A -> B (cols 0..255) ----
  f32x4 acc2[4][2];
  #pragma unroll
  for (int mt = 0; mt < 4; ++mt){ acc2[mt][0] = zf; acc2[mt][1] = zf; }
  mm_stream<16, 2>(A, b1F, wave*2, lane, lrow, lkg, acc2);
  epi_silu<2>(B, wave*32, bsb1, lrow, lkg, acc2);
  __syncthreads();

  // ---- blk2: 256 -> 170 (pad 176), B as A-operand, + row-max + atomic ----
  f32x4 acc3[4][2];
  #pragma unroll
  for (int mt = 0; mt < 4; ++mt){ acc3[mt][0] = zf; acc3[mt][1] = zf; }
  {
    const int xr = (lrow & 7) << 4;
    const bool has2 = wave < 3;                    // wave+8 < 11
    #pragma unroll
    for (int t = 0; t < 8; ++t){
      h8v a[4];
      int koff = ((t*4 + lkg) << 4) ^ xr;
      #pragma unroll
      for (int mt = 0; mt < 4; ++mt)
        a[mt] = *(const h8v*)(B + (mt*16 + lrow)*1024 + koff);
      {
        h8v w = *(const h8v*)&b2F[((size_t)(wave*8 + t)*64 + lane)*8];
        #pragma unroll
        for (int mt = 0; mt < 4; ++mt)
          acc3[mt][0] = __builtin_amdgcn_mfma_f32_16x16x32_f16(a[mt], w, acc3[mt][0], 0, 0, 0);
      }
      if (has2){
        h8v w = *(const h8v*)&b2F[((size_t)((wave + 8)*8 + t)*64 + lane)*8];
        #pragma unroll
        for (int mt = 0; mt < 4; ++mt)
          acc3[mt][1] = __builtin_amdgcn_mfma_f32_16x16x32_f16(a[mt], w, acc3[mt][1], 0, 0, 0);
      }
    }
    #pragma unroll
    for (int t = 0; t < 2; ++t){
      if (t == 1 && !has2) break;
      int c = ((t == 0) ? wave : wave + 8)*16 + lrow;
      if (c < 170){
        float bb = bsb2[c];
        float mx = -INFINITY;
        #pragma unroll
        for (int mt = 0; mt < 4; ++mt)
          #pragma unroll
          for (int rg = 0; rg < 4; ++rg)
            mx = fmaxf(mx, silu_fast(acc3[mt][t][rg] + bb));
        mx = fmaxf(mx, __shfl_xor(mx, 16));
        mx = fmaxf(mx, __shfl_xor(mx, 32));
        if (lkg == 0)
          atomicMax(&outmax[b*5440 + k*170 + c], f2mono(mx));
      }
    }
  }
}

__global__ void finalize_kernel(const unsigned* __restrict__ m, float* __restrict__ out, int n){
  int i = blockIdx.x*blockDim.x + threadIdx.x;
  if (i < n) out[i] = mono2f(m[i]);
}

// ---------------- launch ----------------
extern "C" void kernel_launch(void* const* d_in, const int* in_sizes, int n_in,
                              void* d_out, int out_size, void* d_ws, size_t ws_size,
                              hipStream_t stream){
  const float* pts    = (const float*)d_in[0];
  const float* t_cw   = (const float*)d_in[1];
  const float* t_cb   = (const float*)d_in[2];
  const float* t_g1   = (const float*)d_in[3];
  const float* t_b1   = (const float*)d_in[4];
  const float* t_d1w  = (const float*)d_in[5];
  const float* t_d1b  = (const float*)d_in[6];
  const float* t_g2   = (const float*)d_in[7];
  const float* t_b2   = (const float*)d_in[8];
  const float* t_d2w  = (const float*)d_in[9];
  const float* t_d2b  = (const float*)d_in[10];
  const float* c1_w   = (const float*)d_in[11];
  const float* c1_b   = (const float*)d_in[12];
  const float* c1_g   = (const float*)d_in[13];
  const float* c1_be  = (const float*)d_in[14];
  const float* res_w  = (const float*)d_in[15];
  const float* res_b  = (const float*)d_in[16];
  const float* b0_w   = (const float*)d_in[17];
  const float* b0_b   = (const float*)d_in[18];
  const float* b0_g   = (const float*)d_in[19];
  const float* b0_be  = (const float*)d_in[20];
  const float* b1_w   = (const float*)d_in[21];
  const float* b1_b   = (const float*)d_in[22];
  const float* b1_g   = (const float*)d_in[23];
  const float* b1_be  = (const float*)d_in[24];
  const float* b2_w   = (const float*)d_in[25];
  const float* b2_b   = (const float*)d_in[26];
  const float* b2_g   = (const float*)d_in[27];
  const float* b2_be  = (const float*)d_in[28];

  char* ws = (char*)d_ws;
  float*    T9   = (float*)(ws + OFF_T9);
  unsigned* XM   = (unsigned*)(ws + OFF_XM);
  float4*   PC4  = (float4*)(ws + OFF_PC4);
  unsigned* OUTM = (unsigned*)(ws + OFF_OUT);
  f16* C1F  = (f16*)(ws + OFF_C1T);
  f16* B0C  = (f16*)(ws + OFF_B0C);
  f16* B1F  = (f16*)(ws + OFF_B1T);
  f16* B2F  = (f16*)(ws + OFF_B2T);
  float* BS1  = (float*)(ws + OFF_BS1);
  float* BS0  = (float*)(ws + OFF_BS0);
  float* BSB1 = (float*)(ws + OFF_BSB1);
  float* BSB2 = (float*)(ws + OFF_BSB2);
  f16* F9   = (f16*)(ws + OFF_F9);

  hipMemsetAsync(ws + OFF_XM, 0, 4*128*4, stream);
  hipMemsetAsync(ws + OFF_OUT, 0, 21760*4, stream);

  prep_kernel<<<512, 256, 0, stream>>>(c1_w, b0_w, b1_w, b2_w,
                                       c1_b, c1_g, c1_be, res_b,
                                       b0_b, b0_g, b0_be,
                                       b1_b, b1_g, b1_be,
                                       b2_b, b2_g, b2_be,
                                       C1F, B1F, B2F,
                                       BS1, BS0, BSB1, BSB2);
  composeb0_kernel<<<256, 256, 0, stream>>>(res_w, b0_w, b0_g, B0C);
  tnet1_kernel<<<dim3(4,4), dim3(128,4), 0, stream>>>(pts, t_cw, t_cb, t_g1, t_b1, XM);
  tnet2_kernel<<<4, 128, 0, stream>>>(XM, t_d1w, t_d1b, t_g2, t_b2, t_d2w, t_d2b, T9);
  pc_kernel<<<32, 256, 0, stream>>>(pts, T9, PC4);
  group_kernel<<<2048, 256, 0, stream>>>(PC4, F9);
  mlp_kernel<<<4096, 512, 0, stream>>>(F9, C1F, B0C, B1F, B2F,
                                       BS1, BS0, BSB1, BSB2, OUTM);
  finalize_kernel<<<(out_size + 255)/256, 256, 0, stream>>>(OUTM, (float*)d_out, out_size);
}